// Round 1
// baseline (533.493 us; speedup 1.0000x reference)
//
#include <hip/hip_runtime.h>
#include <cfloat>
#include <cmath>

#define EPS 1e-6f

constexpr int B = 8, H = 12, N = 1024, D = 64, K = 256;
constexpr int NM1 = N - 1;   // 1023
constexpr int KP1 = K + 1;   // 257

// ---------------------------------------------------------------------------
// Kernel 1: cls[b,j] = sum_h attn[b,h,0,1+j] * ||value[b,h,1+j,:]||
// One wave (64 lanes) per (b,j); lane = d index (D==64).
// ---------------------------------------------------------------------------
__global__ __launch_bounds__(256) void k1_cls(const float* __restrict__ attn,
                                              const float* __restrict__ value,
                                              float* __restrict__ cls) {
    int wave = (blockIdx.x * blockDim.x + threadIdx.x) >> 6;
    int lane = threadIdx.x & 63;
    if (wave >= B * NM1) return;
    int b = wave / NM1;
    int j = wave - b * NM1;
    float acc = 0.f;
    for (int h = 0; h < H; ++h) {
        const float* vrow = value + (((size_t)(b * H + h) * N) + (1 + j)) * D;
        float v = vrow[lane];
        float ss = v * v;
        #pragma unroll
        for (int off = 32; off > 0; off >>= 1)
            ss += __shfl_xor(ss, off, 64);
        float nrm = sqrtf(ss);
        float a = attn[(size_t)(b * H + h) * N * N + 1 + j];  // row 0 of attn
        acc += a * nrm;
    }
    if (lane == 0) cls[b * NM1 + j] = acc;
}

// ---------------------------------------------------------------------------
// Kernel 2: per-batch normalize + log (+mask). In-place over cls -> logits.
// One block per batch.
// ---------------------------------------------------------------------------
__global__ __launch_bounds__(256) void k2_logits(float* __restrict__ cls,
                                                 const int* __restrict__ mask) {
    int b = blockIdx.x;
    int tid = threadIdx.x;
    __shared__ float red[256];
    float s = 0.f;
    for (int j = tid; j < NM1; j += 256) s += cls[b * NM1 + j];
    red[tid] = s;
    __syncthreads();
    for (int off = 128; off > 0; off >>= 1) {
        if (tid < off) red[tid] += red[tid + off];
        __syncthreads();
    }
    float denom = red[0] + EPS;
    const float mask_value = -(FLT_MAX * 0.5f);
    for (int j = tid; j < NM1; j += 256) {
        float pl = logf(cls[b * NM1 + j] / denom + EPS);
        if (mask[b * N + 1 + j] == 0) pl = mask_value;
        cls[b * NM1 + j] = pl;
    }
}

// ---------------------------------------------------------------------------
// Kernel 3: sampled[b,k] = argmax_j (logits[b,j] + gumbel(u[b,k,j])) + 1
// One wave per (b,k). First-occurrence tie-break like jnp.argmax.
// ---------------------------------------------------------------------------
__global__ __launch_bounds__(256) void k3_sample(const float* __restrict__ logits,
                                                 const float* __restrict__ gu,
                                                 int* __restrict__ sampled) {
    int wave = (blockIdx.x * blockDim.x + threadIdx.x) >> 6;
    int lane = threadIdx.x & 63;
    if (wave >= B * K) return;
    int b = wave / K;
    int k = wave - b * K;
    const float* u  = gu + (size_t)(b * K + k) * NM1;
    const float* lg = logits + b * NM1;
    float best = -FLT_MAX;
    int bestj = 0x7fffffff;
    for (int j = lane; j < NM1; j += 64) {
        float g = -logf(-logf(u[j] + EPS) + EPS);
        float v = lg[j] + g;
        if (v > best) { best = v; bestj = j; }   // strict > keeps first occurrence
    }
    #pragma unroll
    for (int off = 32; off > 0; off >>= 1) {
        float ov = __shfl_xor(best, off, 64);
        int   oj = __shfl_xor(bestj, off, 64);
        if (ov > best || (ov == best && oj < bestj)) { best = ov; bestj = oj; }
    }
    if (lane == 0) sampled[b * K + k] = bestj + 1;
}

// ---------------------------------------------------------------------------
// Kernel 4: per batch: bitonic-sort 256 sampled ids, dedup (dups -> 0, zeros
// sorted to front), emit ids (+leading 0) and mask (+leading 1).
// One block (256 threads) per batch.
// ---------------------------------------------------------------------------
__global__ __launch_bounds__(256) void k4_sort(const int* __restrict__ sampled,
                                               int* __restrict__ ws_ids,
                                               float* __restrict__ out_ids,
                                               float* __restrict__ out_mask) {
    int b = blockIdx.x;
    int tid = threadIdx.x;
    __shared__ int s[K];
    __shared__ int sc[K];
    __shared__ int uniq[K];
    s[tid] = sampled[b * K + tid];
    for (int size = 2; size <= K; size <<= 1) {
        for (int stride = size >> 1; stride > 0; stride >>= 1) {
            __syncthreads();
            int partner = tid ^ stride;
            if (partner > tid) {
                bool asc = ((tid & size) == 0);
                int a = s[tid], c = s[partner];
                if ((a > c) == asc) { s[tid] = c; s[partner] = a; }
            }
        }
    }
    __syncthreads();
    int v = s[tid];
    int flag = (tid == 0) ? 1 : ((v != s[tid - 1]) ? 1 : 0);
    sc[tid] = flag;
    for (int off = 1; off < K; off <<= 1) {
        __syncthreads();
        int add = (tid >= off) ? sc[tid - off] : 0;
        __syncthreads();
        sc[tid] += add;
    }
    __syncthreads();
    int total = sc[K - 1];   // number of unique values
    int nz = K - total;      // leading zeros
    uniq[tid] = 0;
    __syncthreads();
    if (flag) uniq[nz + sc[tid] - 1] = v;
    __syncthreads();
    int idv = uniq[tid];
    ws_ids[b * KP1 + 1 + tid]   = idv;
    out_ids[b * KP1 + 1 + tid]  = (float)idv;
    out_mask[b * KP1 + 1 + tid] = idv ? 1.0f : 0.0f;
    if (tid == 0) {
        ws_ids[b * KP1]   = 0;
        out_ids[b * KP1]  = 0.0f;
        out_mask[b * KP1] = 1.0f;
    }
}

// ---------------------------------------------------------------------------
// Kernel 5: new_attn[b,h,t,:] = attn[b,h,ids[b,t],:]. One block per output row,
// float4 per thread (256 threads * 16 B = 4 KB row).
// ---------------------------------------------------------------------------
__global__ __launch_bounds__(256) void k5_gather(const float* __restrict__ attn,
                                                 const int* __restrict__ ids,
                                                 float* __restrict__ out) {
    int row = blockIdx.x;            // (b*H + h) * KP1 + t
    int bh = row / KP1;
    int t = row - bh * KP1;
    int b = bh / H;
    int id = ids[b * KP1 + t];
    const float4* src = (const float4*)(attn + ((size_t)bh * N + id) * N);
    float4* dst = (float4*)(out + (size_t)row * N);
    dst[threadIdx.x] = src[threadIdx.x];
}

extern "C" void kernel_launch(void* const* d_in, const int* in_sizes, int n_in,
                              void* d_out, int out_size, void* d_ws, size_t ws_size,
                              hipStream_t stream) {
    const float* attn  = (const float*)d_in[0];
    const float* value = (const float*)d_in[1];
    const int*   mask  = (const int*)d_in[2];
    const float* gu    = (const float*)d_in[3];
    // d_in[4] = output_num_tokens (256, structure hardcoded)

    float* out       = (float*)d_out;
    float* out_attn  = out;                                 // B*H*KP1*N
    float* out_mask  = out + (size_t)B * H * KP1 * N;       // B*KP1
    float* out_ids   = out_mask + B * KP1;                  // B*KP1

    float* ws_cls     = (float*)d_ws;                       // B*NM1 (reused as logits)
    int*   ws_sampled = (int*)(ws_cls + B * NM1);           // B*K
    int*   ws_ids     = ws_sampled + B * K;                 // B*KP1

    // 1. cls_attn weighted by value norms: one wave per (b,j)
    k1_cls<<<(B * NM1 * 64 + 255) / 256, 256, 0, stream>>>(attn, value, ws_cls);
    // 2. normalize + log -> pseudo_logits (in-place)
    k2_logits<<<B, 256, 0, stream>>>(ws_cls, mask);
    // 3. gumbel argmax: one wave per (b,k)
    k3_sample<<<(B * K * 64 + 255) / 256, 256, 0, stream>>>(ws_cls, gu, ws_sampled);
    // 4. sort + dedup + emit ids/mask
    k4_sort<<<B, K, 0, stream>>>(ws_sampled, ws_ids, out_ids, out_mask);
    // 5. gather attn rows
    k5_gather<<<B * H * KP1, 256, 0, stream>>>(attn, ws_ids, out_attn);
}

// Round 2
// 531.204 us; speedup vs baseline: 1.0043x; 1.0043x over previous
//
#include <hip/hip_runtime.h>
#include <cfloat>
#include <cmath>

#define EPS 1e-6f

constexpr int B = 8, H = 12, N = 1024, D = 64, K = 256;
constexpr int NM1 = N - 1;   // 1023
constexpr int KP1 = K + 1;   // 257

// ---------------------------------------------------------------------------
// Kernel 1: cls[b,j] = sum_h attn[b,h,0,1+j] * ||value[b,h,1+j,:]||
// 4 (b,j) pairs per wave: 16-lane group per row, float4 per lane (D=64).
// ---------------------------------------------------------------------------
__global__ __launch_bounds__(256) void k1_cls(const float* __restrict__ attn,
                                              const float* __restrict__ value,
                                              float* __restrict__ cls) {
    int gtid = blockIdx.x * 256 + threadIdx.x;
    int wave = gtid >> 6;
    int lane = threadIdx.x & 63;
    int q = wave * 4 + (lane >> 4);      // global (b,j) index, uniform per 16-group
    int sub = lane & 15;
    if (q >= B * NM1) return;
    int b = q / NM1;
    int j = q - b * NM1;
    float acc = 0.f;
    for (int h = 0; h < H; ++h) {
        const float4* vrow = (const float4*)(value + (((size_t)(b * H + h)) * N + 1 + j) * D);
        float4 v = vrow[sub];
        float ss = v.x * v.x + v.y * v.y + v.z * v.z + v.w * v.w;
        ss += __shfl_xor(ss, 1, 64);
        ss += __shfl_xor(ss, 2, 64);
        ss += __shfl_xor(ss, 4, 64);
        ss += __shfl_xor(ss, 8, 64);
        float a = attn[(size_t)(b * H + h) * N * N + 1 + j];   // row 0 of attn
        acc += a * sqrtf(ss);
    }
    if (sub == 0) cls[q] = acc;
}

// ---------------------------------------------------------------------------
// Kernel 2+3 fused: per-block denom recompute (bit-identical across blocks),
// logits on the fly, gumbel argmax. One wave per (b,k); 4 k's of one b per block.
// ---------------------------------------------------------------------------
__global__ __launch_bounds__(256) void k23_sample(const float* __restrict__ cls,
                                                  const int* __restrict__ mask,
                                                  const float* __restrict__ gu,
                                                  int* __restrict__ sampled) {
    int b = blockIdx.x >> 6;               // 64 blocks per batch
    int k = ((blockIdx.x & 63) << 2) + (threadIdx.x >> 6);
    int lane = threadIdx.x & 63;

    __shared__ float red[256];
    float s = 0.f;
    for (int j = threadIdx.x; j < NM1; j += 256) s += cls[b * NM1 + j];
    red[threadIdx.x] = s;
    __syncthreads();
    for (int off = 128; off > 0; off >>= 1) {
        if (threadIdx.x < off) red[threadIdx.x] += red[threadIdx.x + off];
        __syncthreads();
    }
    float denom = red[0] + EPS;
    const float mask_value = -(FLT_MAX * 0.5f);

    const float* u  = gu + (size_t)(b * K + k) * NM1;
    const float* cb = cls + b * NM1;
    float best = -FLT_MAX;
    int bestj = 0x7fffffff;
    for (int j = lane; j < NM1; j += 64) {
        float pl = logf(cb[j] / denom + EPS);
        if (mask[b * N + 1 + j] == 0) pl = mask_value;
        float g = -logf(-logf(u[j] + EPS) + EPS);
        float v = pl + g;
        if (v > best) { best = v; bestj = j; }   // strict > keeps first occurrence
    }
    #pragma unroll
    for (int off = 32; off > 0; off >>= 1) {
        float ov = __shfl_xor(best, off, 64);
        int   oj = __shfl_xor(bestj, off, 64);
        if (ov > best || (ov == best && oj < bestj)) { best = ov; bestj = oj; }
    }
    if (lane == 0) sampled[b * K + k] = bestj + 1;
}

// ---------------------------------------------------------------------------
// Kernel 4: per batch: bitonic-sort 256 sampled ids, dedup (dups -> 0, zeros
// sorted to front), emit ids (+leading 0) and mask (+leading 1).
// ---------------------------------------------------------------------------
__global__ __launch_bounds__(256) void k4_sort(const int* __restrict__ sampled,
                                               int* __restrict__ ws_ids,
                                               float* __restrict__ out_ids,
                                               float* __restrict__ out_mask) {
    int b = blockIdx.x;
    int tid = threadIdx.x;
    __shared__ int s[K];
    __shared__ int sc[K];
    __shared__ int uniq[K];
    s[tid] = sampled[b * K + tid];
    for (int size = 2; size <= K; size <<= 1) {
        for (int stride = size >> 1; stride > 0; stride >>= 1) {
            __syncthreads();
            int partner = tid ^ stride;
            if (partner > tid) {
                bool asc = ((tid & size) == 0);
                int a = s[tid], c = s[partner];
                if ((a > c) == asc) { s[tid] = c; s[partner] = a; }
            }
        }
    }
    __syncthreads();
    int v = s[tid];
    int flag = (tid == 0) ? 1 : ((v != s[tid - 1]) ? 1 : 0);
    sc[tid] = flag;
    for (int off = 1; off < K; off <<= 1) {
        __syncthreads();
        int add = (tid >= off) ? sc[tid - off] : 0;
        __syncthreads();
        sc[tid] += add;
    }
    __syncthreads();
    int total = sc[K - 1];   // number of unique values
    int nz = K - total;      // leading zeros
    uniq[tid] = 0;
    __syncthreads();
    if (flag) uniq[nz + sc[tid] - 1] = v;
    __syncthreads();
    int idv = uniq[tid];
    ws_ids[b * KP1 + 1 + tid]   = idv;
    out_ids[b * KP1 + 1 + tid]  = (float)idv;
    out_mask[b * KP1 + 1 + tid] = idv ? 1.0f : 0.0f;
    if (tid == 0) {
        ws_ids[b * KP1]   = 0;
        out_ids[b * KP1]  = 0.0f;
        out_mask[b * KP1] = 1.0f;
    }
}

// ---------------------------------------------------------------------------
// Kernel 5: new_attn[b,h,t,:] = attn[b,h,ids[b,t],:]. One block per output row,
// float4 per thread (256 threads * 16 B = 4 KB row).
// ---------------------------------------------------------------------------
__global__ __launch_bounds__(256) void k5_gather(const float* __restrict__ attn,
                                                 const int* __restrict__ ids,
                                                 float* __restrict__ out) {
    int row = blockIdx.x;            // (b*H + h) * KP1 + t
    int bh = row / KP1;
    int t = row - bh * KP1;
    int b = bh / H;
    int id = ids[b * KP1 + t];
    const float4* src = (const float4*)(attn + ((size_t)bh * N + id) * N);
    float4* dst = (float4*)(out + (size_t)row * N);
    dst[threadIdx.x] = src[threadIdx.x];
}

extern "C" void kernel_launch(void* const* d_in, const int* in_sizes, int n_in,
                              void* d_out, int out_size, void* d_ws, size_t ws_size,
                              hipStream_t stream) {
    const float* attn  = (const float*)d_in[0];
    const float* value = (const float*)d_in[1];
    const int*   mask  = (const int*)d_in[2];
    const float* gu    = (const float*)d_in[3];
    // d_in[4] = output_num_tokens (256, structure hardcoded)

    float* out       = (float*)d_out;
    float* out_attn  = out;                                 // B*H*KP1*N
    float* out_mask  = out + (size_t)B * H * KP1 * N;       // B*KP1
    float* out_ids   = out_mask + B * KP1;                  // B*KP1

    float* ws_cls     = (float*)d_ws;                       // B*NM1
    int*   ws_sampled = (int*)(ws_cls + B * NM1);           // B*K
    int*   ws_ids     = ws_sampled + B * K;                 // B*KP1

    // 1. cls_attn weighted by value norms: 4 (b,j) per wave
    k1_cls<<<(B * NM1 / 4 * 64 + 255) / 256, 256, 0, stream>>>(attn, value, ws_cls);
    // 2+3. normalize+log fused into gumbel argmax: one wave per (b,k)
    k23_sample<<<B * (K / 4), 256, 0, stream>>>(ws_cls, mask, gu, ws_sampled);
    // 4. sort + dedup + emit ids/mask
    k4_sort<<<B, K, 0, stream>>>(ws_sampled, ws_ids, out_ids, out_mask);
    // 5. gather attn rows
    k5_gather<<<B * H * KP1, 256, 0, stream>>>(attn, ws_ids, out_attn);
}

// Round 3
// 529.502 us; speedup vs baseline: 1.0075x; 1.0032x over previous
//
#include <hip/hip_runtime.h>
#include <cfloat>
#include <cmath>

#define EPS 1e-6f

constexpr int B = 8, H = 12, N = 1024, D = 64, K = 256;
constexpr int NM1 = N - 1;   // 1023
constexpr int KP1 = K + 1;   // 257

// ---------------------------------------------------------------------------
// Kernel 1: cls[b,j] = sum_h attn[b,h,0,1+j] * ||value[b,h,1+j,:]||
// 4 (b,j) pairs per wave: 16-lane group per row, float4 per lane (D=64).
// ---------------------------------------------------------------------------
__global__ __launch_bounds__(256) void k1_cls(const float* __restrict__ attn,
                                              const float* __restrict__ value,
                                              float* __restrict__ cls) {
    int gtid = blockIdx.x * 256 + threadIdx.x;
    int wave = gtid >> 6;
    int lane = threadIdx.x & 63;
    int q = wave * 4 + (lane >> 4);      // global (b,j) index, uniform per 16-group
    int sub = lane & 15;
    if (q >= B * NM1) return;
    int b = q / NM1;
    int j = q - b * NM1;
    float acc = 0.f;
    for (int h = 0; h < H; ++h) {
        const float4* vrow = (const float4*)(value + (((size_t)(b * H + h)) * N + 1 + j) * D);
        float4 v = vrow[sub];
        float ss = v.x * v.x + v.y * v.y + v.z * v.z + v.w * v.w;
        ss += __shfl_xor(ss, 1, 64);
        ss += __shfl_xor(ss, 2, 64);
        ss += __shfl_xor(ss, 4, 64);
        ss += __shfl_xor(ss, 8, 64);
        float a = attn[(size_t)(b * H + h) * N * N + 1 + j];   // row 0 of attn
        acc += a * sqrtf(ss);
    }
    if (sub == 0) cls[q] = acc;
}

// ---------------------------------------------------------------------------
// Kernel 2+3 fused: denom reduce -> logits staged in LDS (once per block,
// bit-identical expression across blocks) -> gumbel argmax. One wave per
// (b,k); 4 k's of one b per block (64 blocks per batch).
// ---------------------------------------------------------------------------
__global__ __launch_bounds__(256) void k23_sample(const float* __restrict__ cls,
                                                  const int* __restrict__ mask,
                                                  const float* __restrict__ gu,
                                                  int* __restrict__ sampled) {
    int b = blockIdx.x >> 6;               // 64 blocks per batch
    int k = ((blockIdx.x & 63) << 2) + (threadIdx.x >> 6);
    int lane = threadIdx.x & 63;
    int tid = threadIdx.x;

    __shared__ float red[256];
    __shared__ float slog[NM1];            // 4 KB; j=lane+64*it -> 2-way bank alias (free)

    const float* cb = cls + b * NM1;
    float s = 0.f;
    for (int j = tid; j < NM1; j += 256) s += cb[j];
    red[tid] = s;
    __syncthreads();
    for (int off = 128; off > 0; off >>= 1) {
        if (tid < off) red[tid] += red[tid + off];
        __syncthreads();
    }
    float denom = red[0] + EPS;
    const float mask_value = -(FLT_MAX * 0.5f);

    for (int j = tid; j < NM1; j += 256) {
        float pl = logf(cb[j] / denom + EPS);
        if (mask[b * N + 1 + j] == 0) pl = mask_value;
        slog[j] = pl;
    }
    __syncthreads();

    const float* u = gu + (size_t)(b * K + k) * NM1;
    float best = -FLT_MAX;
    int bestj = 0x7fffffff;
    for (int j = lane; j < NM1; j += 64) {
        float g = -logf(-logf(u[j] + EPS) + EPS);
        float v = slog[j] + g;
        if (v > best) { best = v; bestj = j; }   // strict > keeps first occurrence
    }
    #pragma unroll
    for (int off = 32; off > 0; off >>= 1) {
        float ov = __shfl_xor(best, off, 64);
        int   oj = __shfl_xor(bestj, off, 64);
        if (ov > best || (ov == best && oj < bestj)) { best = ov; bestj = oj; }
    }
    if (lane == 0) sampled[b * K + k] = bestj + 1;
}

// ---------------------------------------------------------------------------
// Kernel 4: per batch: bitonic-sort 256 sampled ids, dedup (dups -> 0, zeros
// sorted to front), emit ids (+leading 0) and mask (+leading 1).
// ---------------------------------------------------------------------------
__global__ __launch_bounds__(256) void k4_sort(const int* __restrict__ sampled,
                                               int* __restrict__ ws_ids,
                                               float* __restrict__ out_ids,
                                               float* __restrict__ out_mask) {
    int b = blockIdx.x;
    int tid = threadIdx.x;
    __shared__ int s[K];
    __shared__ int sc[2][K];
    __shared__ int uniq[K];
    s[tid] = sampled[b * K + tid];
    for (int size = 2; size <= K; size <<= 1) {
        for (int stride = size >> 1; stride > 0; stride >>= 1) {
            __syncthreads();
            int partner = tid ^ stride;
            if (partner > tid) {
                bool asc = ((tid & size) == 0);
                int a = s[tid], c = s[partner];
                if ((a > c) == asc) { s[tid] = c; s[partner] = a; }
            }
        }
    }
    __syncthreads();
    int v = s[tid];
    int flag = (tid == 0) ? 1 : ((v != s[tid - 1]) ? 1 : 0);
    // double-buffered Hillis-Steele scan: one barrier per round
    sc[0][tid] = flag;
    int cur = 0;
    for (int off = 1; off < K; off <<= 1) {
        __syncthreads();
        int val = sc[cur][tid];
        if (tid >= off) val += sc[cur][tid - off];
        sc[cur ^ 1][tid] = val;
        cur ^= 1;
    }
    __syncthreads();
    int total = sc[cur][K - 1];   // number of unique values
    int nz = K - total;           // leading zeros
    uniq[tid] = 0;
    __syncthreads();
    if (flag) uniq[nz + sc[cur][tid] - 1] = v;
    __syncthreads();
    int idv = uniq[tid];
    ws_ids[b * KP1 + 1 + tid]   = idv;
    out_ids[b * KP1 + 1 + tid]  = (float)idv;
    out_mask[b * KP1 + 1 + tid] = idv ? 1.0f : 0.0f;
    if (tid == 0) {
        ws_ids[b * KP1]   = 0;
        out_ids[b * KP1]  = 0.0f;
        out_mask[b * KP1] = 1.0f;
    }
}

// ---------------------------------------------------------------------------
// Kernel 5: new_attn[b,h,t,:] = attn[b,h,ids[b,t],:]. One block per output row,
// float4 per thread (256 threads * 16 B = 4 KB row).
// ---------------------------------------------------------------------------
__global__ __launch_bounds__(256) void k5_gather(const float* __restrict__ attn,
                                                 const int* __restrict__ ids,
                                                 float* __restrict__ out) {
    int row = blockIdx.x;            // (b*H + h) * KP1 + t
    int bh = row / KP1;
    int t = row - bh * KP1;
    int b = bh / H;
    int id = ids[b * KP1 + t];
    const float4* src = (const float4*)(attn + ((size_t)bh * N + id) * N);
    float4* dst = (float4*)(out + (size_t)row * N);
    dst[threadIdx.x] = src[threadIdx.x];
}

extern "C" void kernel_launch(void* const* d_in, const int* in_sizes, int n_in,
                              void* d_out, int out_size, void* d_ws, size_t ws_size,
                              hipStream_t stream) {
    const float* attn  = (const float*)d_in[0];
    const float* value = (const float*)d_in[1];
    const int*   mask  = (const int*)d_in[2];
    const float* gu    = (const float*)d_in[3];
    // d_in[4] = output_num_tokens (256, structure hardcoded)

    float* out       = (float*)d_out;
    float* out_attn  = out;                                 // B*H*KP1*N
    float* out_mask  = out + (size_t)B * H * KP1 * N;       // B*KP1
    float* out_ids   = out_mask + B * KP1;                  // B*KP1

    float* ws_cls     = (float*)d_ws;                       // B*NM1
    int*   ws_sampled = (int*)(ws_cls + B * NM1);           // B*K
    int*   ws_ids     = ws_sampled + B * K;                 // B*KP1

    // 1. cls_attn weighted by value norms: 4 (b,j) per wave
    k1_cls<<<(B * NM1 / 4 * 64 + 255) / 256, 256, 0, stream>>>(attn, value, ws_cls);
    // 2+3. logits in LDS + gumbel argmax: one wave per (b,k)
    k23_sample<<<B * (K / 4), 256, 0, stream>>>(ws_cls, mask, gu, ws_sampled);
    // 4. sort + dedup + emit ids/mask
    k4_sort<<<B, K, 0, stream>>>(ws_sampled, ws_ids, out_ids, out_mask);
    // 5. gather attn rows
    k5_gather<<<B * H * KP1, 256, 0, stream>>>(attn, ws_ids, out_attn);
}